// Round 1
// baseline (1558.903 us; speedup 1.0000x reference)
//
#include <hip/hip_runtime.h>
#include <math.h>

#define NEG_SLOPE 0.2f

// ---------------- Kernel A: h1 = x @ W1 (+ per-node attention dots) ----------------
// block = 256 threads (one thread per output column), NPB nodes per block.
// threads 0..63 = head 0 (wave 0), 64..127 head 1, etc.
template <int NPB>
__global__ __launch_bounds__(256) void gemm1_att(
    const float* __restrict__ x, const float* __restrict__ W1,
    const float* __restrict__ att_s, const float* __restrict__ att_d,
    float* __restrict__ h1, float* __restrict__ a1s, float* __restrict__ a1d, int N) {
  __shared__ float xs[NPB][128];
  const int n0 = blockIdx.x * NPB;
  const int t = threadIdx.x;
  for (int i = t; i < NPB * 128; i += 256) {
    int node = n0 + (i >> 7);
    xs[i >> 7][i & 127] = (node < N) ? x[(size_t)node * 128 + (i & 127)] : 0.0f;
  }
  __syncthreads();
  float acc[NPB];
#pragma unroll
  for (int i = 0; i < NPB; i++) acc[i] = 0.0f;
  const int j = t;  // output channel 0..255
  for (int k = 0; k < 128; k++) {
    float w = W1[k * 256 + j];
#pragma unroll
    for (int i = 0; i < NPB; i++) acc[i] = fmaf(xs[i][k], w, acc[i]);
  }
  const float asj = att_s[j];
  const float adj = att_d[j];
  const int head = j >> 6;
  const int lane = j & 63;
#pragma unroll
  for (int i = 0; i < NPB; i++) {
    int node = n0 + i;
    if (node < N) h1[(size_t)node * 256 + j] = acc[i];
    float vs = acc[i] * asj;
    float vd = acc[i] * adj;
#pragma unroll
    for (int off = 32; off > 0; off >>= 1) {
      vs += __shfl_down(vs, off, 64);
      vd += __shfl_down(vd, off, 64);
    }
    if (lane == 0 && node < N) {
      a1s[node * 4 + head] = vs;
      a1d[node * 4 + head] = vd;
    }
  }
}

// ---------------- init output buffer with broadcast bias ----------------
__global__ void init_bias(float* __restrict__ out, const float* __restrict__ b, int total, int C) {
  int i = blockIdx.x * 256 + threadIdx.x;
  if (i < total) out[i] = b[i % C];
}

// ---------------- Kernel B: edge softmax numerators + denominators (layer 1) --------
__global__ void edge_softmax1(const int* __restrict__ src, const int* __restrict__ dst,
                              const float* __restrict__ a1s, const float* __restrict__ a1d,
                              float* __restrict__ ex1, float* __restrict__ den1, int E, int ET) {
  int e = blockIdx.x * 256 + threadIdx.x;
  if (e >= ET) return;
  int s, d;
  if (e < E) { s = src[e]; d = dst[e]; } else { s = d = e - E; }
  float4 as = *(const float4*)(a1s + (size_t)s * 4);
  float4 ad = *(const float4*)(a1d + (size_t)d * 4);
  float l0 = as.x + ad.x, l1 = as.y + ad.y, l2 = as.z + ad.z, l3 = as.w + ad.w;
  l0 = l0 > 0.f ? l0 : NEG_SLOPE * l0;
  l1 = l1 > 0.f ? l1 : NEG_SLOPE * l1;
  l2 = l2 > 0.f ? l2 : NEG_SLOPE * l2;
  l3 = l3 > 0.f ? l3 : NEG_SLOPE * l3;
  float e0 = expf(l0), e1 = expf(l1), e2 = expf(l2), e3 = expf(l3);
  *(float4*)(ex1 + (size_t)e * 4) = make_float4(e0, e1, e2, e3);
  atomicAdd(den1 + (size_t)d * 4 + 0, e0);
  atomicAdd(den1 + (size_t)d * 4 + 1, e1);
  atomicAdd(den1 + (size_t)d * 4 + 2, e2);
  atomicAdd(den1 + (size_t)d * 4 + 3, e3);
}

// ---------------- Kernel C: scatter-aggregate layer 1 (one wave per edge) ----------
__global__ __launch_bounds__(256) void aggregate1(
    const int* __restrict__ src, const int* __restrict__ dst, const float* __restrict__ h1,
    const float* __restrict__ ex1, const float* __restrict__ den1,
    float* __restrict__ out1, int E, int ET) {
  int e = blockIdx.x * 4 + (threadIdx.x >> 6);
  int lane = threadIdx.x & 63;
  if (e >= ET) return;
  int s, d;
  if (e < E) { s = src[e]; d = dst[e]; } else { s = d = e - E; }
  float4 ex = *(const float4*)(ex1 + (size_t)e * 4);
  float4 den = *(const float4*)(den1 + (size_t)d * 4);
  float a0 = ex.x / den.x, a1 = ex.y / den.y, a2 = ex.z / den.z, a3 = ex.w / den.w;
  const float* hs = h1 + (size_t)s * 256;
  float* od = out1 + (size_t)d * 256;
  atomicAdd(od + lane, a0 * hs[lane]);
  atomicAdd(od + 64 + lane, a1 * hs[64 + lane]);
  atomicAdd(od + 128 + lane, a2 * hs[128 + lane]);
  atomicAdd(od + 192 + lane, a3 * hs[192 + lane]);
}

// ---------------- Kernel D: bias + ELU + GEMM2 + layer-2 attention dots ------------
// one wave per node, 4 nodes per block. W2 [256,10] staged in LDS.
__global__ __launch_bounds__(256) void layer2_prep(
    const float* __restrict__ out1, const float* __restrict__ b1, const float* __restrict__ W2,
    const float* __restrict__ att_s2, const float* __restrict__ att_d2,
    float* __restrict__ h2, float* __restrict__ a2s, float* __restrict__ a2d, int N) {
  __shared__ float w2s[2560];
  int t = threadIdx.x;
  for (int i = t; i < 2560; i += 256) w2s[i] = W2[i];
  __syncthreads();
  int wave = t >> 6, lane = t & 63;
  int n = blockIdx.x * 4 + wave;
  if (n >= N) return;
  float4 v = *(const float4*)(out1 + (size_t)n * 256 + lane * 4);
  float4 bb = *(const float4*)(b1 + lane * 4);
  float c[4] = {v.x + bb.x, v.y + bb.y, v.z + bb.z, v.w + bb.w};
#pragma unroll
  for (int k = 0; k < 4; k++) c[k] = c[k] > 0.f ? c[k] : expm1f(c[k]);
  float p[10];
#pragma unroll
  for (int jj = 0; jj < 10; jj++) p[jj] = 0.f;
#pragma unroll
  for (int k = 0; k < 4; k++) {
    const float* wrow = w2s + (lane * 4 + k) * 10;
#pragma unroll
    for (int jj = 0; jj < 10; jj++) p[jj] = fmaf(c[k], wrow[jj], p[jj]);
  }
#pragma unroll
  for (int jj = 0; jj < 10; jj++) {
#pragma unroll
    for (int off = 32; off > 0; off >>= 1) p[jj] += __shfl_down(p[jj], off, 64);
  }
  if (lane == 0) {
    float ds = 0.f, dd = 0.f;
#pragma unroll
    for (int jj = 0; jj < 10; jj++) {
      h2[(size_t)n * 10 + jj] = p[jj];
      ds = fmaf(p[jj], att_s2[jj], ds);
      dd = fmaf(p[jj], att_d2[jj], dd);
    }
    a2s[n] = ds;
    a2d[n] = dd;
  }
}

// ---------------- Kernel E: edge softmax layer 2 ----------------
__global__ void edge_softmax2(const int* __restrict__ src, const int* __restrict__ dst,
                              const float* __restrict__ a2s, const float* __restrict__ a2d,
                              float* __restrict__ ex2, float* __restrict__ den2, int E, int ET) {
  int e = blockIdx.x * 256 + threadIdx.x;
  if (e >= ET) return;
  int s, d;
  if (e < E) { s = src[e]; d = dst[e]; } else { s = d = e - E; }
  float l = a2s[s] + a2d[d];
  l = l > 0.f ? l : NEG_SLOPE * l;
  float ex = expf(l);
  ex2[e] = ex;
  atomicAdd(den2 + d, ex);
}

// ---------------- Kernel F: scatter-aggregate layer 2 (thread per edge) ------------
__global__ void aggregate2(const int* __restrict__ src, const int* __restrict__ dst,
                           const float* __restrict__ h2, const float* __restrict__ ex2,
                           const float* __restrict__ den2, float* __restrict__ out, int E, int ET) {
  int e = blockIdx.x * 256 + threadIdx.x;
  if (e >= ET) return;
  int s, d;
  if (e < E) { s = src[e]; d = dst[e]; } else { s = d = e - E; }
  float alpha = ex2[e] / den2[d];
  const float* hs = h2 + (size_t)s * 10;
  float* od = out + (size_t)d * 10;
#pragma unroll
  for (int jj = 0; jj < 10; jj++) atomicAdd(od + jj, alpha * hs[jj]);
}

extern "C" void kernel_launch(void* const* d_in, const int* in_sizes, int n_in,
                              void* d_out, int out_size, void* d_ws, size_t ws_size,
                              hipStream_t stream) {
  const float* x = (const float*)d_in[0];
  const int* ei = (const int*)d_in[1];
  const float* W1 = (const float*)d_in[2];
  const float* as1 = (const float*)d_in[3];
  const float* ad1 = (const float*)d_in[4];
  const float* b1 = (const float*)d_in[5];
  const float* W2 = (const float*)d_in[6];
  const float* as2 = (const float*)d_in[7];
  const float* ad2 = (const float*)d_in[8];
  const float* b2 = (const float*)d_in[9];
  float* out = (float*)d_out;

  const int N = in_sizes[0] / 128;   // 50000
  const int E = in_sizes[1] / 2;     // 800000
  const int ET = E + N;              // with self-loops
  const int* srcp = ei;
  const int* dstp = ei + E;

  float* ws = (float*)d_ws;
  size_t off = 0;
  auto alloc = [&](size_t nf) {
    float* p = ws + off;
    off += (nf + 63) & ~(size_t)63;
    return p;
  };
  float* h1 = alloc((size_t)N * 256);
  float* out1 = alloc((size_t)N * 256);
  float* a1s = alloc((size_t)N * 4);
  float* a1d = alloc((size_t)N * 4);
  float* ex1 = alloc((size_t)ET * 4);
  float* den1 = alloc((size_t)N * 4);
  float* h2 = alloc((size_t)N * 10);
  float* a2sv = alloc((size_t)N);
  float* a2dv = alloc((size_t)N);
  float* ex2 = alloc((size_t)ET);
  float* den2 = alloc((size_t)N);

  hipMemsetAsync(den1, 0, (size_t)N * 4 * sizeof(float), stream);
  hipMemsetAsync(den2, 0, (size_t)N * sizeof(float), stream);

  gemm1_att<8><<<(N + 7) / 8, 256, 0, stream>>>(x, W1, as1, ad1, h1, a1s, a1d, N);
  init_bias<<<((N * 256) + 255) / 256, 256, 0, stream>>>(out1, b1, N * 256, 256);
  edge_softmax1<<<(ET + 255) / 256, 256, 0, stream>>>(srcp, dstp, a1s, a1d, ex1, den1, E, ET);
  aggregate1<<<(ET + 3) / 4, 256, 0, stream>>>(srcp, dstp, h1, ex1, den1, out1, E, ET);
  layer2_prep<<<(N + 3) / 4, 256, 0, stream>>>(out1, b1, W2, as2, ad2, h2, a2sv, a2dv, N);
  edge_softmax2<<<(ET + 255) / 256, 256, 0, stream>>>(srcp, dstp, a2sv, a2dv, ex2, den2, E, ET);
  init_bias<<<((N * 10) + 255) / 256, 256, 0, stream>>>(out, b2, N * 10, 10);
  aggregate2<<<(ET + 255) / 256, 256, 0, stream>>>(srcp, dstp, h2, ex2, den2, out, E, ET);
}

// Round 2
// 684.793 us; speedup vs baseline: 2.2765x; 2.2765x over previous
//
#include <hip/hip_runtime.h>
#include <math.h>

#define NEG_SLOPE 0.2f

// ---------------- Kernel A: h1 = x @ W1 (+ per-node attention dots) ----------------
template <int NPB>
__global__ __launch_bounds__(256) void gemm1_att(
    const float* __restrict__ x, const float* __restrict__ W1,
    const float* __restrict__ att_s, const float* __restrict__ att_d,
    float* __restrict__ h1, float* __restrict__ a1s, float* __restrict__ a1d, int N) {
  __shared__ float xs[NPB][128];
  const int n0 = blockIdx.x * NPB;
  const int t = threadIdx.x;
  for (int i = t; i < NPB * 128; i += 256) {
    int node = n0 + (i >> 7);
    xs[i >> 7][i & 127] = (node < N) ? x[(size_t)node * 128 + (i & 127)] : 0.0f;
  }
  __syncthreads();
  float acc[NPB];
#pragma unroll
  for (int i = 0; i < NPB; i++) acc[i] = 0.0f;
  const int j = t;
  for (int k = 0; k < 128; k++) {
    float w = W1[k * 256 + j];
#pragma unroll
    for (int i = 0; i < NPB; i++) acc[i] = fmaf(xs[i][k], w, acc[i]);
  }
  const float asj = att_s[j];
  const float adj = att_d[j];
  const int head = j >> 6;
  const int lane = j & 63;
#pragma unroll
  for (int i = 0; i < NPB; i++) {
    int node = n0 + i;
    if (node < N) h1[(size_t)node * 256 + j] = acc[i];
    float vs = acc[i] * asj;
    float vd = acc[i] * adj;
#pragma unroll
    for (int off = 32; off > 0; off >>= 1) {
      vs += __shfl_down(vs, off, 64);
      vd += __shfl_down(vd, off, 64);
    }
    if (lane == 0 && node < N) {
      a1s[node * 4 + head] = vs;
      a1d[node * 4 + head] = vd;
    }
  }
}

// ---------------- CSR build ----------------
__global__ void hist_deg(const int* __restrict__ dst, int* __restrict__ deg, int E, int ET) {
  int e = blockIdx.x * 256 + threadIdx.x;
  if (e >= ET) return;
  int d = (e < E) ? dst[e] : e - E;
  atomicAdd(deg + d, 1);
}

__global__ void scan_local(const int* __restrict__ deg, int* __restrict__ excl,
                           int* __restrict__ bsum, int N) {
  __shared__ int s[256];
  int i = blockIdx.x * 256 + threadIdx.x;
  int v = (i < N) ? deg[i] : 0;
  s[threadIdx.x] = v;
  __syncthreads();
  for (int off = 1; off < 256; off <<= 1) {
    int t = (threadIdx.x >= off) ? s[threadIdx.x - off] : 0;
    __syncthreads();
    s[threadIdx.x] += t;
    __syncthreads();
  }
  if (i < N) excl[i] = s[threadIdx.x] - v;
  if (threadIdx.x == 255) bsum[blockIdx.x] = s[255];
}

__global__ void scan_bsum(int* __restrict__ bsum, int nb) {
  __shared__ int s[256];
  int v = (threadIdx.x < nb) ? bsum[threadIdx.x] : 0;
  s[threadIdx.x] = v;
  __syncthreads();
  for (int off = 1; off < 256; off <<= 1) {
    int t = (threadIdx.x >= off) ? s[threadIdx.x - off] : 0;
    __syncthreads();
    s[threadIdx.x] += t;
    __syncthreads();
  }
  if (threadIdx.x < nb) bsum[threadIdx.x] = s[threadIdx.x] - v;  // exclusive
}

__global__ void scan_add(const int* __restrict__ excl, const int* __restrict__ bsum,
                         int* __restrict__ rowptr, int* __restrict__ cursor, int N, int ET) {
  int i = blockIdx.x * 256 + threadIdx.x;
  if (i < N) {
    int r = excl[i] + bsum[blockIdx.x];
    rowptr[i] = r;
    cursor[i] = r;
  }
  if (i == 0) rowptr[N] = ET;
}

__global__ void scatter_edges(const int* __restrict__ src, const int* __restrict__ dst,
                              int* __restrict__ cursor, int2* __restrict__ elist, int E, int ET) {
  int e = blockIdx.x * 256 + threadIdx.x;
  if (e >= ET) return;
  int s, d;
  if (e < E) { s = src[e]; d = dst[e]; } else { s = d = e - E; }
  int pos = atomicAdd(cursor + d, 1);
  elist[pos] = make_int2(s, e);
}

// ---------------- Kernel B: edge softmax numerators (layer 1, no atomics) ----------
__global__ void edge_softmax1(const int* __restrict__ src, const int* __restrict__ dst,
                              const float* __restrict__ a1s, const float* __restrict__ a1d,
                              float* __restrict__ ex1, int E, int ET) {
  int e = blockIdx.x * 256 + threadIdx.x;
  if (e >= ET) return;
  int s, d;
  if (e < E) { s = src[e]; d = dst[e]; } else { s = d = e - E; }
  float4 as = *(const float4*)(a1s + (size_t)s * 4);
  float4 ad = *(const float4*)(a1d + (size_t)d * 4);
  float l0 = as.x + ad.x, l1 = as.y + ad.y, l2 = as.z + ad.z, l3 = as.w + ad.w;
  l0 = l0 > 0.f ? l0 : NEG_SLOPE * l0;
  l1 = l1 > 0.f ? l1 : NEG_SLOPE * l1;
  l2 = l2 > 0.f ? l2 : NEG_SLOPE * l2;
  l3 = l3 > 0.f ? l3 : NEG_SLOPE * l3;
  *(float4*)(ex1 + (size_t)e * 4) = make_float4(expf(l0), expf(l1), expf(l2), expf(l3));
}

// ---------------- Kernel C: CSR gather-aggregate layer 1, fused with
// bias1 + ELU + GEMM2 (W2 in LDS) + layer-2 attention dots. Block per node. ----------
__global__ __launch_bounds__(256) void agg1_fused(
    const int* __restrict__ rowptr, const int2* __restrict__ elist,
    const float* __restrict__ h1, const float* __restrict__ ex1,
    const float* __restrict__ b1, const float* __restrict__ W2,
    const float* __restrict__ as2, const float* __restrict__ ad2,
    float* __restrict__ h2, float* __restrict__ a2s, float* __restrict__ a2d, int N) {
  __shared__ float w2s[2560];
  __shared__ float dpart[4][4];
  __shared__ float wred[4][10];
  __shared__ float hred[10];
  const int t = threadIdx.x;
  for (int i = t; i < 2560; i += 256) w2s[i] = W2[i];
  const int n = blockIdx.x;
  const int row = rowptr[n];
  const int deg = rowptr[n + 1] - row;
  const int wave = t >> 6, lane = t & 63;

  // pass 1: softmax denominators (4 heads)
  float4 dl = make_float4(0.f, 0.f, 0.f, 0.f);
  for (int j = t; j < deg; j += 256) {
    int e = elist[row + j].y;
    float4 ex = *(const float4*)(ex1 + (size_t)e * 4);
    dl.x += ex.x; dl.y += ex.y; dl.z += ex.z; dl.w += ex.w;
  }
#pragma unroll
  for (int off = 32; off > 0; off >>= 1) {
    dl.x += __shfl_down(dl.x, off, 64);
    dl.y += __shfl_down(dl.y, off, 64);
    dl.z += __shfl_down(dl.z, off, 64);
    dl.w += __shfl_down(dl.w, off, 64);
  }
  if (lane == 0) {
    dpart[wave][0] = dl.x; dpart[wave][1] = dl.y;
    dpart[wave][2] = dl.z; dpart[wave][3] = dl.w;
  }
  __syncthreads();
  const int head = t >> 6;
  float den = dpart[0][head] + dpart[1][head] + dpart[2][head] + dpart[3][head];
  float invden = 1.0f / den;

  // pass 2: accumulate alpha * h1[src] ; thread t owns channel t
  float acc = 0.f;
  for (int j = 0; j < deg; j++) {
    int2 se = elist[row + j];
    float exv = ex1[(size_t)se.y * 4 + head];
    acc = fmaf(exv * invden, h1[(size_t)se.x * 256 + t], acc);
  }

  // epilogue: bias + ELU -> c ; p[10] = c * W2[t][:] ; block-reduce
  float c = acc + b1[t];
  c = c > 0.f ? c : expm1f(c);
  float p[10];
#pragma unroll
  for (int jj = 0; jj < 10; jj++) p[jj] = c * w2s[t * 10 + jj];
#pragma unroll
  for (int jj = 0; jj < 10; jj++) {
#pragma unroll
    for (int off = 32; off > 0; off >>= 1) p[jj] += __shfl_down(p[jj], off, 64);
  }
  if (lane == 0) {
#pragma unroll
    for (int jj = 0; jj < 10; jj++) wred[wave][jj] = p[jj];
  }
  __syncthreads();
  if (t < 10) {
    float tot = wred[0][t] + wred[1][t] + wred[2][t] + wred[3][t];
    h2[(size_t)n * 10 + t] = tot;
    hred[t] = tot;
  }
  __syncthreads();
  if (t == 0) {
    float ds = 0.f, dd = 0.f;
#pragma unroll
    for (int jj = 0; jj < 10; jj++) {
      ds = fmaf(hred[jj], as2[jj], ds);
      dd = fmaf(hred[jj], ad2[jj], dd);
    }
    a2s[n] = ds;
    a2d[n] = dd;
  }
}

// ---------------- Kernel E: edge softmax layer 2 (no atomics) ----------------
__global__ void edge_softmax2(const int* __restrict__ src, const int* __restrict__ dst,
                              const float* __restrict__ a2s, const float* __restrict__ a2d,
                              float* __restrict__ ex2, int E, int ET) {
  int e = blockIdx.x * 256 + threadIdx.x;
  if (e >= ET) return;
  int s, d;
  if (e < E) { s = src[e]; d = dst[e]; } else { s = d = e - E; }
  float l = a2s[s] + a2d[d];
  l = l > 0.f ? l : NEG_SLOPE * l;
  ex2[e] = expf(l);
}

// ---------------- Kernel F: CSR gather-aggregate layer 2 (wave per node) ----------
__global__ __launch_bounds__(256) void agg2_csr(
    const int* __restrict__ rowptr, const int2* __restrict__ elist,
    const float* __restrict__ h2, const float* __restrict__ ex2,
    const float* __restrict__ b2, float* __restrict__ out, int N) {
  int wave = threadIdx.x >> 6, lane = threadIdx.x & 63;
  int n = blockIdx.x * 4 + wave;
  if (n >= N) return;
  int row = rowptr[n];
  int deg = rowptr[n + 1] - row;
  float dl = 0.f;
  for (int j = lane; j < deg; j += 64) dl += ex2[elist[row + j].y];
#pragma unroll
  for (int off = 32; off > 0; off >>= 1) dl += __shfl_down(dl, off, 64);
  float inv = 1.0f / __shfl(dl, 0, 64);
  float acc = 0.f;
  for (int j = 0; j < deg; j++) {
    int2 se = elist[row + j];
    float a = ex2[se.y] * inv;
    if (lane < 10) acc = fmaf(a, h2[(size_t)se.x * 10 + lane], acc);
  }
  if (lane < 10) out[(size_t)n * 10 + lane] = acc + b2[lane];
}

extern "C" void kernel_launch(void* const* d_in, const int* in_sizes, int n_in,
                              void* d_out, int out_size, void* d_ws, size_t ws_size,
                              hipStream_t stream) {
  const float* x = (const float*)d_in[0];
  const int* ei = (const int*)d_in[1];
  const float* W1 = (const float*)d_in[2];
  const float* as1 = (const float*)d_in[3];
  const float* ad1 = (const float*)d_in[4];
  const float* b1 = (const float*)d_in[5];
  const float* W2 = (const float*)d_in[6];
  const float* as2 = (const float*)d_in[7];
  const float* ad2 = (const float*)d_in[8];
  const float* b2 = (const float*)d_in[9];
  float* out = (float*)d_out;

  const int N = in_sizes[0] / 128;   // 50000
  const int E = in_sizes[1] / 2;     // 800000
  const int ET = E + N;
  const int* srcp = ei;
  const int* dstp = ei + E;

  char* ws = (char*)d_ws;
  size_t off = 0;
  auto alloc = [&](size_t nbytes) {
    char* p = ws + off;
    off += (nbytes + 255) & ~(size_t)255;
    return p;
  };
  float* h1 = (float*)alloc((size_t)N * 256 * 4);
  float* a1s = (float*)alloc((size_t)N * 4 * 4);
  float* a1d = (float*)alloc((size_t)N * 4 * 4);
  float* ex1 = (float*)alloc((size_t)ET * 4 * 4);
  float* h2 = (float*)alloc((size_t)N * 10 * 4);
  float* a2sv = (float*)alloc((size_t)N * 4);
  float* a2dv = (float*)alloc((size_t)N * 4);
  float* ex2 = (float*)alloc((size_t)ET * 4);
  int* deg = (int*)alloc((size_t)N * 4);
  int* excl = (int*)alloc((size_t)N * 4);
  int* bsum = (int*)alloc(256 * 4);
  int* rowptr = (int*)alloc((size_t)(N + 1) * 4);
  int* cursor = (int*)alloc((size_t)N * 4);
  int2* elist = (int2*)alloc((size_t)ET * 8);

  const int nb = (N + 255) / 256;

  hipMemsetAsync(deg, 0, (size_t)N * 4, stream);

  // CSR build
  hist_deg<<<(ET + 255) / 256, 256, 0, stream>>>(dstp, deg, E, ET);
  scan_local<<<nb, 256, 0, stream>>>(deg, excl, bsum, N);
  scan_bsum<<<1, 256, 0, stream>>>(bsum, nb);
  scan_add<<<nb, 256, 0, stream>>>(excl, bsum, rowptr, cursor, N, ET);
  scatter_edges<<<(ET + 255) / 256, 256, 0, stream>>>(srcp, dstp, cursor, elist, E, ET);

  // layer 1
  gemm1_att<8><<<(N + 7) / 8, 256, 0, stream>>>(x, W1, as1, ad1, h1, a1s, a1d, N);
  edge_softmax1<<<(ET + 255) / 256, 256, 0, stream>>>(srcp, dstp, a1s, a1d, ex1, E, ET);
  agg1_fused<<<N, 256, 0, stream>>>(rowptr, elist, h1, ex1, b1, W2, as2, ad2,
                                    h2, a2sv, a2dv, N);
  // layer 2
  edge_softmax2<<<(ET + 255) / 256, 256, 0, stream>>>(srcp, dstp, a2sv, a2dv, ex2, E, ET);
  agg2_csr<<<(N + 3) / 4, 256, 0, stream>>>(rowptr, elist, h2, ex2, b2, out, N);
}

// Round 3
// 542.543 us; speedup vs baseline: 2.8733x; 1.2622x over previous
//
#include <hip/hip_runtime.h>
#include <hip/hip_fp16.h>
#include <math.h>

#define NEG_SLOPE 0.2f

// ---------------- Kernel A: h1 = x @ W1 (+ per-node attention dots), fp16 h1 out ----
template <int NPB>
__global__ __launch_bounds__(256) void gemm1_att(
    const float* __restrict__ x, const float* __restrict__ W1,
    const float* __restrict__ att_s, const float* __restrict__ att_d,
    __half* __restrict__ h1, float* __restrict__ a1s, float* __restrict__ a1d, int N) {
  __shared__ float xs[NPB][128];
  const int n0 = blockIdx.x * NPB;
  const int t = threadIdx.x;
  // stage x rows as float4
  for (int i = t; i < NPB * 32; i += 256) {
    int node = n0 + (i >> 5);
    float4 v = make_float4(0.f, 0.f, 0.f, 0.f);
    if (node < N) v = ((const float4*)x)[(size_t)node * 32 + (i & 31)];
    ((float4*)xs)[i] = v;
  }
  __syncthreads();
  float acc[NPB];
#pragma unroll
  for (int i = 0; i < NPB; i++) acc[i] = 0.0f;
  const int j = t;
  for (int k = 0; k < 128; k++) {
    float w = W1[k * 256 + j];
#pragma unroll
    for (int i = 0; i < NPB; i++) acc[i] = fmaf(xs[i][k], w, acc[i]);
  }
  const float asj = att_s[j];
  const float adj = att_d[j];
  const int head = j >> 6;
  const int lane = j & 63;
#pragma unroll
  for (int i = 0; i < NPB; i++) {
    int node = n0 + i;
    if (node < N) h1[(size_t)node * 256 + j] = __float2half(acc[i]);
    float vs = acc[i] * asj;
    float vd = acc[i] * adj;
#pragma unroll
    for (int off = 32; off > 0; off >>= 1) {
      vs += __shfl_down(vs, off, 64);
      vd += __shfl_down(vd, off, 64);
    }
    if (lane == 0 && node < N) {
      a1s[node * 4 + head] = vs;
      a1d[node * 4 + head] = vd;
    }
  }
}

// ---------------- CSR build ----------------
__global__ void hist_deg(const int* __restrict__ dst, int* __restrict__ deg, int E, int ET) {
  int e = blockIdx.x * 256 + threadIdx.x;
  if (e >= ET) return;
  int d = (e < E) ? dst[e] : e - E;
  atomicAdd(deg + d, 1);
}

__global__ void scan_local(const int* __restrict__ deg, int* __restrict__ excl,
                           int* __restrict__ bsum, int N) {
  __shared__ int s[256];
  int i = blockIdx.x * 256 + threadIdx.x;
  int v = (i < N) ? deg[i] : 0;
  s[threadIdx.x] = v;
  __syncthreads();
  for (int off = 1; off < 256; off <<= 1) {
    int t = (threadIdx.x >= off) ? s[threadIdx.x - off] : 0;
    __syncthreads();
    s[threadIdx.x] += t;
    __syncthreads();
  }
  if (i < N) excl[i] = s[threadIdx.x] - v;
  if (threadIdx.x == 255) bsum[blockIdx.x] = s[255];
}

__global__ void scan_bsum(int* __restrict__ bsum, int nb) {
  __shared__ int s[256];
  int v = (threadIdx.x < nb) ? bsum[threadIdx.x] : 0;
  s[threadIdx.x] = v;
  __syncthreads();
  for (int off = 1; off < 256; off <<= 1) {
    int t = (threadIdx.x >= off) ? s[threadIdx.x - off] : 0;
    __syncthreads();
    s[threadIdx.x] += t;
    __syncthreads();
  }
  if (threadIdx.x < nb) bsum[threadIdx.x] = s[threadIdx.x] - v;  // exclusive
}

__global__ void scan_add(const int* __restrict__ excl, const int* __restrict__ bsum,
                         int* __restrict__ rowptr, int* __restrict__ cursor, int N, int ET) {
  int i = blockIdx.x * 256 + threadIdx.x;
  if (i < N) {
    int r = excl[i] + bsum[blockIdx.x];
    rowptr[i] = r;
    cursor[i] = r;
  }
  if (i == 0) rowptr[N] = ET;
}

__global__ void scatter_edges(const int* __restrict__ src, const int* __restrict__ dst,
                              int* __restrict__ cursor, int2* __restrict__ elist, int E, int ET) {
  int e = blockIdx.x * 256 + threadIdx.x;
  if (e >= ET) return;
  int s, d;
  if (e < E) { s = src[e]; d = dst[e]; } else { s = d = e - E; }
  int pos = atomicAdd(cursor + d, 1);
  elist[pos] = make_int2(s, e);
}

// ---------------- Kernel B: edge softmax numerators (layer 1) ----------
__global__ void edge_softmax1(const int* __restrict__ src, const int* __restrict__ dst,
                              const float* __restrict__ a1s, const float* __restrict__ a1d,
                              float* __restrict__ ex1, int E, int ET) {
  int e = blockIdx.x * 256 + threadIdx.x;
  if (e >= ET) return;
  int s, d;
  if (e < E) { s = src[e]; d = dst[e]; } else { s = d = e - E; }
  float4 as = *(const float4*)(a1s + (size_t)s * 4);
  float4 ad = *(const float4*)(a1d + (size_t)d * 4);
  float l0 = as.x + ad.x, l1 = as.y + ad.y, l2 = as.z + ad.z, l3 = as.w + ad.w;
  l0 = l0 > 0.f ? l0 : NEG_SLOPE * l0;
  l1 = l1 > 0.f ? l1 : NEG_SLOPE * l1;
  l2 = l2 > 0.f ? l2 : NEG_SLOPE * l2;
  l3 = l3 > 0.f ? l3 : NEG_SLOPE * l3;
  *(float4*)(ex1 + (size_t)e * 4) = make_float4(expf(l0), expf(l1), expf(l2), expf(l3));
}

// ---------------- Kernel C: CSR gather-aggregate layer 1, single-pass den+acc,
// fused bias1 + ELU + GEMM2 (W2 in LDS) + layer-2 attention dots. Block per node. ----
__global__ __launch_bounds__(256) void agg1_fused(
    const int* __restrict__ rowptr, const int2* __restrict__ elist,
    const __half* __restrict__ h1, const float* __restrict__ ex1,
    const float* __restrict__ b1, const float* __restrict__ W2,
    const float* __restrict__ as2, const float* __restrict__ ad2,
    float* __restrict__ h2, float* __restrict__ a2s, float* __restrict__ a2d, int N) {
  __shared__ float w2s[2560];
  __shared__ float wred[4][10];
  __shared__ float hred[10];
  const int t = threadIdx.x;
  for (int i = t; i < 2560; i += 256) w2s[i] = W2[i];
  const int n = blockIdx.x;
  const int row = rowptr[n];
  const int deg = rowptr[n + 1] - row;
  const int head = t >> 6;
  const int lane = t & 63;
  const int2* el = elist + row;

  // single pass: unnormalized acc + denominator (den identical across lanes of a wave)
  float den = 0.f, acc = 0.f;
  int j = 0;
  for (; j + 4 <= deg; j += 4) {
    int2 se0 = el[j], se1 = el[j + 1], se2 = el[j + 2], se3 = el[j + 3];
    float e0 = ex1[(size_t)se0.y * 4 + head];
    float e1 = ex1[(size_t)se1.y * 4 + head];
    float e2 = ex1[(size_t)se2.y * 4 + head];
    float e3 = ex1[(size_t)se3.y * 4 + head];
    float g0 = __half2float(h1[(size_t)se0.x * 256 + t]);
    float g1 = __half2float(h1[(size_t)se1.x * 256 + t]);
    float g2 = __half2float(h1[(size_t)se2.x * 256 + t]);
    float g3 = __half2float(h1[(size_t)se3.x * 256 + t]);
    den += (e0 + e1) + (e2 + e3);
    acc = fmaf(e0, g0, fmaf(e1, g1, fmaf(e2, g2, fmaf(e3, g3, acc))));
  }
  for (; j < deg; j++) {
    int2 se = el[j];
    float e0 = ex1[(size_t)se.y * 4 + head];
    float g0 = __half2float(h1[(size_t)se.x * 256 + t]);
    den += e0;
    acc = fmaf(e0, g0, acc);
  }

  // epilogue: normalize + bias + ELU -> c ; p[10] = c * W2[t][:] ; block-reduce
  float c = acc / den + b1[t];
  c = c > 0.f ? c : expm1f(c);
  __syncthreads();  // w2s staged
  float p[10];
#pragma unroll
  for (int jj = 0; jj < 10; jj++) p[jj] = c * w2s[t * 10 + jj];
#pragma unroll
  for (int jj = 0; jj < 10; jj++) {
#pragma unroll
    for (int off = 32; off > 0; off >>= 1) p[jj] += __shfl_down(p[jj], off, 64);
  }
  if (lane == 0) {
#pragma unroll
    for (int jj = 0; jj < 10; jj++) wred[head][jj] = p[jj];
  }
  __syncthreads();
  if (t < 10) {
    float tot = wred[0][t] + wred[1][t] + wred[2][t] + wred[3][t];
    h2[(size_t)n * 16 + t] = tot;  // padded row: one cache line per node
    hred[t] = tot;
  }
  __syncthreads();
  if (t == 0) {
    float ds = 0.f, dd = 0.f;
#pragma unroll
    for (int jj = 0; jj < 10; jj++) {
      ds = fmaf(hred[jj], as2[jj], ds);
      dd = fmaf(hred[jj], ad2[jj], dd);
    }
    a2s[n] = ds;
    a2d[n] = dd;
  }
}

// ---------------- Kernel E: edge softmax layer 2 ----------------
__global__ void edge_softmax2(const int* __restrict__ src, const int* __restrict__ dst,
                              const float* __restrict__ a2s, const float* __restrict__ a2d,
                              float* __restrict__ ex2, int E, int ET) {
  int e = blockIdx.x * 256 + threadIdx.x;
  if (e >= ET) return;
  int s, d;
  if (e < E) { s = src[e]; d = dst[e]; } else { s = d = e - E; }
  float l = a2s[s] + a2d[d];
  l = l > 0.f ? l : NEG_SLOPE * l;
  ex2[e] = expf(l);
}

// ---------------- Kernel F: CSR gather-aggregate layer 2 (wave per node,
// 6 edges in flight: lane = 10*group + channel) ----------
__global__ __launch_bounds__(256) void agg2_csr(
    const int* __restrict__ rowptr, const int2* __restrict__ elist,
    const float* __restrict__ h2, const float* __restrict__ ex2,
    const float* __restrict__ b2, float* __restrict__ out, int N) {
  int wave = threadIdx.x >> 6, lane = threadIdx.x & 63;
  int n = blockIdx.x * 4 + wave;
  if (n >= N) return;
  int row = rowptr[n];
  int deg = rowptr[n + 1] - row;
  const int2* el = elist + row;
  int g = lane / 10;        // 0..5 active, 6 (lanes 60-63) idle
  int c = lane - g * 10;
  float den = 0.f, acc = 0.f;
  if (g < 6) {
    for (int j0 = 0; j0 < deg; j0 += 6) {
      int jj = j0 + g;
      if (jj < deg) {
        int2 se = el[jj];
        float ev = ex2[se.y];
        den += ev;
        acc = fmaf(ev, h2[(size_t)se.x * 16 + c], acc);
      }
    }
  }
  // reduce the 6 groups (channels align mod 10)
  acc += __shfl_down(acc, 30, 64);
  den += __shfl_down(den, 30, 64);
  acc += __shfl_down(acc, 10, 64) + __shfl_down(acc, 20, 64);
  den += __shfl_down(den, 10, 64) + __shfl_down(den, 20, 64);
  if (lane < 10) out[(size_t)n * 10 + lane] = acc / den + b2[lane];
}

extern "C" void kernel_launch(void* const* d_in, const int* in_sizes, int n_in,
                              void* d_out, int out_size, void* d_ws, size_t ws_size,
                              hipStream_t stream) {
  const float* x = (const float*)d_in[0];
  const int* ei = (const int*)d_in[1];
  const float* W1 = (const float*)d_in[2];
  const float* as1 = (const float*)d_in[3];
  const float* ad1 = (const float*)d_in[4];
  const float* b1 = (const float*)d_in[5];
  const float* W2 = (const float*)d_in[6];
  const float* as2 = (const float*)d_in[7];
  const float* ad2 = (const float*)d_in[8];
  const float* b2 = (const float*)d_in[9];
  float* out = (float*)d_out;

  const int N = in_sizes[0] / 128;   // 50000
  const int E = in_sizes[1] / 2;     // 800000
  const int ET = E + N;
  const int* srcp = ei;
  const int* dstp = ei + E;

  char* ws = (char*)d_ws;
  size_t off = 0;
  auto alloc = [&](size_t nbytes) {
    char* p = ws + off;
    off += (nbytes + 255) & ~(size_t)255;
    return p;
  };
  __half* h1 = (__half*)alloc((size_t)N * 256 * 2);
  float* a1s = (float*)alloc((size_t)N * 4 * 4);
  float* a1d = (float*)alloc((size_t)N * 4 * 4);
  float* ex1 = (float*)alloc((size_t)ET * 4 * 4);
  float* h2 = (float*)alloc((size_t)N * 16 * 4);
  float* a2sv = (float*)alloc((size_t)N * 4);
  float* a2dv = (float*)alloc((size_t)N * 4);
  float* ex2 = (float*)alloc((size_t)ET * 4);
  int* deg = (int*)alloc((size_t)N * 4);
  int* excl = (int*)alloc((size_t)N * 4);
  int* bsum = (int*)alloc(256 * 4);
  int* rowptr = (int*)alloc((size_t)(N + 1) * 4);
  int* cursor = (int*)alloc((size_t)N * 4);
  int2* elist = (int2*)alloc((size_t)ET * 8);

  const int nb = (N + 255) / 256;

  hipMemsetAsync(deg, 0, (size_t)N * 4, stream);

  // CSR build
  hist_deg<<<(ET + 255) / 256, 256, 0, stream>>>(dstp, deg, E, ET);
  scan_local<<<nb, 256, 0, stream>>>(deg, excl, bsum, N);
  scan_bsum<<<1, 256, 0, stream>>>(bsum, nb);
  scan_add<<<nb, 256, 0, stream>>>(excl, bsum, rowptr, cursor, N, ET);
  scatter_edges<<<(ET + 255) / 256, 256, 0, stream>>>(srcp, dstp, cursor, elist, E, ET);

  // layer 1
  gemm1_att<16><<<(N + 15) / 16, 256, 0, stream>>>(x, W1, as1, ad1, h1, a1s, a1d, N);
  edge_softmax1<<<(ET + 255) / 256, 256, 0, stream>>>(srcp, dstp, a1s, a1d, ex1, E, ET);
  agg1_fused<<<N, 256, 0, stream>>>(rowptr, elist, h1, ex1, b1, W2, as2, ad2,
                                    h2, a2sv, a2dv, N);
  // layer 2
  edge_softmax2<<<(ET + 255) / 256, 256, 0, stream>>>(srcp, dstp, a2sv, a2dv, ex2, E, ET);
  agg2_csr<<<(N + 3) / 4, 256, 0, stream>>>(rowptr, elist, h2, ex2, b2, out, N);
}

// Round 4
// 382.989 us; speedup vs baseline: 4.0704x; 1.4166x over previous
//
#include <hip/hip_runtime.h>
#include <hip/hip_fp16.h>
#include <math.h>

#define NEG_SLOPE 0.2f

// ---------------- Kernel A: h1 = x @ W1 (+ per-node attention dots), fp16 h1 out ----
template <int NPB>
__global__ __launch_bounds__(256) void gemm1_att(
    const float* __restrict__ x, const float* __restrict__ W1,
    const float* __restrict__ att_s, const float* __restrict__ att_d,
    __half* __restrict__ h1, float* __restrict__ a1s, float* __restrict__ a1d, int N) {
  __shared__ float xs[NPB][128];
  const int n0 = blockIdx.x * NPB;
  const int t = threadIdx.x;
  for (int i = t; i < NPB * 32; i += 256) {
    int node = n0 + (i >> 5);
    float4 v = make_float4(0.f, 0.f, 0.f, 0.f);
    if (node < N) v = ((const float4*)x)[(size_t)node * 32 + (i & 31)];
    ((float4*)xs)[i] = v;
  }
  __syncthreads();
  float acc[NPB];
#pragma unroll
  for (int i = 0; i < NPB; i++) acc[i] = 0.0f;
  const int j = t;
  for (int k = 0; k < 128; k++) {
    float w = W1[k * 256 + j];
#pragma unroll
    for (int i = 0; i < NPB; i++) acc[i] = fmaf(xs[i][k], w, acc[i]);
  }
  const float asj = att_s[j];
  const float adj = att_d[j];
  const int head = j >> 6;
  const int lane = j & 63;
#pragma unroll
  for (int i = 0; i < NPB; i++) {
    int node = n0 + i;
    if (node < N) h1[(size_t)node * 256 + j] = __float2half(acc[i]);
    float vs = acc[i] * asj;
    float vd = acc[i] * adj;
#pragma unroll
    for (int off = 32; off > 0; off >>= 1) {
      vs += __shfl_down(vs, off, 64);
      vd += __shfl_down(vd, off, 64);
    }
    if (lane == 0 && node < N) {
      a1s[node * 4 + head] = vs;
      a1d[node * 4 + head] = vd;
    }
  }
}

// ---------------- CSR build ----------------
__global__ void hist_deg(const int* __restrict__ dst, int* __restrict__ deg, int E, int ET) {
  int e = blockIdx.x * 256 + threadIdx.x;
  if (e >= ET) return;
  int d = (e < E) ? dst[e] : e - E;
  atomicAdd(deg + d, 1);
}

__global__ void scan_local(const int* __restrict__ deg, int* __restrict__ excl,
                           int* __restrict__ bsum, int N) {
  __shared__ int s[256];
  int i = blockIdx.x * 256 + threadIdx.x;
  int v = (i < N) ? deg[i] : 0;
  s[threadIdx.x] = v;
  __syncthreads();
  for (int off = 1; off < 256; off <<= 1) {
    int t = (threadIdx.x >= off) ? s[threadIdx.x - off] : 0;
    __syncthreads();
    s[threadIdx.x] += t;
    __syncthreads();
  }
  if (i < N) excl[i] = s[threadIdx.x] - v;
  if (threadIdx.x == 255) bsum[blockIdx.x] = s[255];
}

__global__ void scan_bsum(int* __restrict__ bsum, int nb) {
  __shared__ int s[256];
  int v = (threadIdx.x < nb) ? bsum[threadIdx.x] : 0;
  s[threadIdx.x] = v;
  __syncthreads();
  for (int off = 1; off < 256; off <<= 1) {
    int t = (threadIdx.x >= off) ? s[threadIdx.x - off] : 0;
    __syncthreads();
    s[threadIdx.x] += t;
    __syncthreads();
  }
  if (threadIdx.x < nb) bsum[threadIdx.x] = s[threadIdx.x] - v;  // exclusive
}

__global__ void scan_add(const int* __restrict__ excl, const int* __restrict__ bsum,
                         int* __restrict__ rowptr, int* __restrict__ cursor, int N, int ET) {
  int i = blockIdx.x * 256 + threadIdx.x;
  if (i < N) {
    int r = excl[i] + bsum[blockIdx.x];
    rowptr[i] = r;
    cursor[i] = r;
  }
  if (i == 0) rowptr[N] = ET;
}

__global__ void scatter_edges(const int* __restrict__ src, const int* __restrict__ dst,
                              int* __restrict__ cursor, int* __restrict__ elist, int E, int ET) {
  int e = blockIdx.x * 256 + threadIdx.x;
  if (e >= ET) return;
  int s, d;
  if (e < E) { s = src[e]; d = dst[e]; } else { s = d = e - E; }
  int pos = atomicAdd(cursor + d, 1);
  elist[pos] = s;
}

// ---------------- Kernel C: wave-per-node CSR aggregate, fused inline softmax +
// bias1 + ELU + GEMM2 (W2 in LDS) + layer-2 attention dots. 4 nodes/block. ----------
__global__ __launch_bounds__(256) void agg1_fused(
    const int* __restrict__ rowptr, const int* __restrict__ elist,
    const __half* __restrict__ h1, const float* __restrict__ a1s,
    const float* __restrict__ a1d, const float* __restrict__ b1,
    const float* __restrict__ W2, const float* __restrict__ as2,
    const float* __restrict__ ad2, float* __restrict__ h2,
    float* __restrict__ a2s, float* __restrict__ a2d, int N) {
  __shared__ float w2s[2560];
  const int t = threadIdx.x;
  for (int i = t; i < 2560; i += 256) w2s[i] = W2[i];
  __syncthreads();

  const int wave = t >> 6, lane = t & 63;
  const int n = blockIdx.x * 4 + wave;
  if (n >= N) return;
  const int row = rowptr[n];
  const int deg = rowptr[n + 1] - row;
  const int* el = elist + row;
  const int hidx = lane >> 4;            // head for channels lane*4..lane*4+3
  const float adh = a1d[n * 4 + hidx];   // uniform within 16-lane group

  float den = 0.f;
  float acc0 = 0.f, acc1 = 0.f, acc2 = 0.f, acc3 = 0.f;
  int j = 0;
  for (; j + 4 <= deg; j += 4) {
    int s0 = el[j], s1 = el[j + 1], s2 = el[j + 2], s3 = el[j + 3];
    float l0 = a1s[s0 * 4 + hidx] + adh;
    float l1 = a1s[s1 * 4 + hidx] + adh;
    float l2 = a1s[s2 * 4 + hidx] + adh;
    float l3 = a1s[s3 * 4 + hidx] + adh;
    uint2 u0 = *(const uint2*)(h1 + (size_t)s0 * 256 + lane * 4);
    uint2 u1 = *(const uint2*)(h1 + (size_t)s1 * 256 + lane * 4);
    uint2 u2 = *(const uint2*)(h1 + (size_t)s2 * 256 + lane * 4);
    uint2 u3 = *(const uint2*)(h1 + (size_t)s3 * 256 + lane * 4);
    l0 = l0 > 0.f ? l0 : NEG_SLOPE * l0;
    l1 = l1 > 0.f ? l1 : NEG_SLOPE * l1;
    l2 = l2 > 0.f ? l2 : NEG_SLOPE * l2;
    l3 = l3 > 0.f ? l3 : NEG_SLOPE * l3;
    float e0 = expf(l0), e1 = expf(l1), e2 = expf(l2), e3 = expf(l3);
    den += (e0 + e1) + (e2 + e3);
    {
      float2 a = __half22float2(*(const __half2*)&u0.x);
      float2 b = __half22float2(*(const __half2*)&u0.y);
      acc0 = fmaf(e0, a.x, acc0); acc1 = fmaf(e0, a.y, acc1);
      acc2 = fmaf(e0, b.x, acc2); acc3 = fmaf(e0, b.y, acc3);
    }
    {
      float2 a = __half22float2(*(const __half2*)&u1.x);
      float2 b = __half22float2(*(const __half2*)&u1.y);
      acc0 = fmaf(e1, a.x, acc0); acc1 = fmaf(e1, a.y, acc1);
      acc2 = fmaf(e1, b.x, acc2); acc3 = fmaf(e1, b.y, acc3);
    }
    {
      float2 a = __half22float2(*(const __half2*)&u2.x);
      float2 b = __half22float2(*(const __half2*)&u2.y);
      acc0 = fmaf(e2, a.x, acc0); acc1 = fmaf(e2, a.y, acc1);
      acc2 = fmaf(e2, b.x, acc2); acc3 = fmaf(e2, b.y, acc3);
    }
    {
      float2 a = __half22float2(*(const __half2*)&u3.x);
      float2 b = __half22float2(*(const __half2*)&u3.y);
      acc0 = fmaf(e3, a.x, acc0); acc1 = fmaf(e3, a.y, acc1);
      acc2 = fmaf(e3, b.x, acc2); acc3 = fmaf(e3, b.y, acc3);
    }
  }
  for (; j < deg; j++) {
    int s0 = el[j];
    float l0 = a1s[s0 * 4 + hidx] + adh;
    uint2 u0 = *(const uint2*)(h1 + (size_t)s0 * 256 + lane * 4);
    l0 = l0 > 0.f ? l0 : NEG_SLOPE * l0;
    float e0 = expf(l0);
    den += e0;
    float2 a = __half22float2(*(const __half2*)&u0.x);
    float2 b = __half22float2(*(const __half2*)&u0.y);
    acc0 = fmaf(e0, a.x, acc0); acc1 = fmaf(e0, a.y, acc1);
    acc2 = fmaf(e0, b.x, acc2); acc3 = fmaf(e0, b.y, acc3);
  }

  // epilogue: normalize + bias + ELU ; p[10] = sum_k c_k * W2[c_k][:] ; wave-reduce
  float inv = 1.0f / den;
  float4 bb = *(const float4*)(b1 + lane * 4);
  float c0 = fmaf(acc0, inv, bb.x);
  float c1 = fmaf(acc1, inv, bb.y);
  float c2 = fmaf(acc2, inv, bb.z);
  float c3 = fmaf(acc3, inv, bb.w);
  c0 = c0 > 0.f ? c0 : expm1f(c0);
  c1 = c1 > 0.f ? c1 : expm1f(c1);
  c2 = c2 > 0.f ? c2 : expm1f(c2);
  c3 = c3 > 0.f ? c3 : expm1f(c3);
  const float* w0 = w2s + (lane * 4 + 0) * 10;
  float p[10];
#pragma unroll
  for (int jj = 0; jj < 10; jj++)
    p[jj] = fmaf(c0, w0[jj], fmaf(c1, w0[10 + jj], fmaf(c2, w0[20 + jj], c3 * w0[30 + jj])));
#pragma unroll
  for (int jj = 0; jj < 10; jj++) {
#pragma unroll
    for (int off = 32; off > 0; off >>= 1) p[jj] += __shfl_down(p[jj], off, 64);
  }
  if (lane == 0) {
    float ds = 0.f, dd = 0.f;
#pragma unroll
    for (int jj = 0; jj < 10; jj++) {
      h2[(size_t)n * 16 + jj] = p[jj];
      ds = fmaf(p[jj], as2[jj], ds);
      dd = fmaf(p[jj], ad2[jj], dd);
    }
    a2s[n] = ds;
    a2d[n] = dd;
  }
}

// ---------------- Kernel F: wave-per-node layer-2 aggregate, inline softmax ----------
__global__ __launch_bounds__(256) void agg2_csr(
    const int* __restrict__ rowptr, const int* __restrict__ elist,
    const float* __restrict__ h2, const float* __restrict__ a2s,
    const float* __restrict__ a2d, const float* __restrict__ b2,
    float* __restrict__ out, int N) {
  int wave = threadIdx.x >> 6, lane = threadIdx.x & 63;
  int n = blockIdx.x * 4 + wave;
  if (n >= N) return;
  int row = rowptr[n];
  int deg = rowptr[n + 1] - row;
  const int* el = elist + row;
  float ad = a2d[n];
  int g = lane / 10;        // 0..5 active, lanes 60-63 idle
  int c = lane - g * 10;
  float den = 0.f, acc = 0.f;
  if (g < 6) {
    for (int j0 = 0; j0 < deg; j0 += 6) {
      int jj = j0 + g;
      if (jj < deg) {
        int s = el[jj];
        float l = a2s[s] + ad;
        l = l > 0.f ? l : NEG_SLOPE * l;
        float ev = expf(l);
        den += ev;
        acc = fmaf(ev, h2[(size_t)s * 16 + c], acc);
      }
    }
  }
  acc += __shfl_down(acc, 30, 64);
  den += __shfl_down(den, 30, 64);
  acc += __shfl_down(acc, 10, 64) + __shfl_down(acc, 20, 64);
  den += __shfl_down(den, 10, 64) + __shfl_down(den, 20, 64);
  if (lane < 10) out[(size_t)n * 10 + lane] = acc / den + b2[lane];
}

extern "C" void kernel_launch(void* const* d_in, const int* in_sizes, int n_in,
                              void* d_out, int out_size, void* d_ws, size_t ws_size,
                              hipStream_t stream) {
  const float* x = (const float*)d_in[0];
  const int* ei = (const int*)d_in[1];
  const float* W1 = (const float*)d_in[2];
  const float* as1 = (const float*)d_in[3];
  const float* ad1 = (const float*)d_in[4];
  const float* b1 = (const float*)d_in[5];
  const float* W2 = (const float*)d_in[6];
  const float* as2 = (const float*)d_in[7];
  const float* ad2 = (const float*)d_in[8];
  const float* b2 = (const float*)d_in[9];
  float* out = (float*)d_out;

  const int N = in_sizes[0] / 128;   // 50000
  const int E = in_sizes[1] / 2;     // 800000
  const int ET = E + N;
  const int* srcp = ei;
  const int* dstp = ei + E;

  char* ws = (char*)d_ws;
  size_t off = 0;
  auto alloc = [&](size_t nbytes) {
    char* p = ws + off;
    off += (nbytes + 255) & ~(size_t)255;
    return p;
  };
  __half* h1 = (__half*)alloc((size_t)N * 256 * 2);
  float* a1s = (float*)alloc((size_t)N * 4 * 4);
  float* a1d = (float*)alloc((size_t)N * 4 * 4);
  float* h2 = (float*)alloc((size_t)N * 16 * 4);
  float* a2sv = (float*)alloc((size_t)N * 4);
  float* a2dv = (float*)alloc((size_t)N * 4);
  int* deg = (int*)alloc((size_t)N * 4);
  int* excl = (int*)alloc((size_t)N * 4);
  int* bsum = (int*)alloc(256 * 4);
  int* rowptr = (int*)alloc((size_t)(N + 1) * 4);
  int* cursor = (int*)alloc((size_t)N * 4);
  int* elist = (int*)alloc((size_t)ET * 4);

  const int nb = (N + 255) / 256;

  hipMemsetAsync(deg, 0, (size_t)N * 4, stream);

  // CSR build
  hist_deg<<<(ET + 255) / 256, 256, 0, stream>>>(dstp, deg, E, ET);
  scan_local<<<nb, 256, 0, stream>>>(deg, excl, bsum, N);
  scan_bsum<<<1, 256, 0, stream>>>(bsum, nb);
  scan_add<<<nb, 256, 0, stream>>>(excl, bsum, rowptr, cursor, N, ET);
  scatter_edges<<<(ET + 255) / 256, 256, 0, stream>>>(srcp, dstp, cursor, elist, E, ET);

  // layer 1 (+ fused layer-2 prep)
  gemm1_att<16><<<(N + 15) / 16, 256, 0, stream>>>(x, W1, as1, ad1, h1, a1s, a1d, N);
  agg1_fused<<<(N + 3) / 4, 256, 0, stream>>>(rowptr, elist, h1, a1s, a1d, b1, W2,
                                              as2, ad2, h2, a2sv, a2dv, N);
  // layer 2
  agg2_csr<<<(N + 3) / 4, 256, 0, stream>>>(rowptr, elist, h2, a2sv, a2dv, b2, out, N);
}

// Round 5
// 344.478 us; speedup vs baseline: 4.5254x; 1.1118x over previous
//
#include <hip/hip_runtime.h>
#include <hip/hip_fp16.h>
#include <math.h>

#define NEG_SLOPE 0.2f

typedef _Float16 half8 __attribute__((ext_vector_type(8)));
typedef float floatx4 __attribute__((ext_vector_type(4)));

// ---------------- pack W1 [128][256] fp32 -> f16 B-fragment order ----------------
// Bpack[((nt*4+ks)*64 + lane)*8 + j] = W1[ks*32 + (lane>>4)*8 + j][nt*16 + (lane&15)]
__global__ __launch_bounds__(256) void pack_W1(const float* __restrict__ W1,
                                               half8* __restrict__ Bpack) {
  int tid = blockIdx.x * 256 + threadIdx.x;  // 4096 total
  int l = tid & 63;
  int ksnt = tid >> 6;
  int ks = ksnt & 3;
  int nt = ksnt >> 2;
  int col = nt * 16 + (l & 15);
  int krow = ks * 32 + (l >> 4) * 8;
  half8 v;
#pragma unroll
  for (int j = 0; j < 8; j++) v[j] = (_Float16)W1[(krow + j) * 256 + col];
  Bpack[tid] = v;
}

// ---------------- Kernel A: h1 = x @ W1 via MFMA, f16 out ----------------
// wave per 16 nodes; 16 N-tiles x 4 K-steps of mfma_f32_16x16x32_f16.
__global__ __launch_bounds__(256) void gemm1_mfma(
    const float* __restrict__ x, const half8* __restrict__ Bpack,
    __half* __restrict__ h1, int N) {
  const int wave = threadIdx.x >> 6, lane = threadIdx.x & 63;
  const int quad = lane >> 4, li = lane & 15;
  const int n0 = (blockIdx.x * 4 + wave) * 16;
  if (n0 >= N) return;
  floatx4 acc[16];
#pragma unroll
  for (int t = 0; t < 16; t++) acc[t] = (floatx4){0.f, 0.f, 0.f, 0.f};
  const float* xrow = x + (size_t)(n0 + li) * 128;
#pragma unroll
  for (int ks = 0; ks < 4; ks++) {
    float4 xa = *(const float4*)(xrow + ks * 32 + quad * 8);
    float4 xb = *(const float4*)(xrow + ks * 32 + quad * 8 + 4);
    half8 a;
    a[0] = (_Float16)xa.x; a[1] = (_Float16)xa.y;
    a[2] = (_Float16)xa.z; a[3] = (_Float16)xa.w;
    a[4] = (_Float16)xb.x; a[5] = (_Float16)xb.y;
    a[6] = (_Float16)xb.z; a[7] = (_Float16)xb.w;
#pragma unroll
    for (int nt = 0; nt < 16; nt++) {
      half8 b = Bpack[(nt * 4 + ks) * 64 + lane];
      acc[nt] = __builtin_amdgcn_mfma_f32_16x16x32_f16(a, b, acc[nt], 0, 0, 0);
    }
  }
  // C/D: row(m) = quad*4 + reg, col(n) = nt*16 + li
#pragma unroll
  for (int nt = 0; nt < 16; nt++) {
#pragma unroll
    for (int r = 0; r < 4; r++) {
      h1[(size_t)(n0 + quad * 4 + r) * 256 + nt * 16 + li] = __float2half(acc[nt][r]);
    }
  }
}

// ---------------- attention dots from h1: a1s/a1d [N][4] ----------------
__global__ __launch_bounds__(256) void att_dots(
    const __half* __restrict__ h1, const float* __restrict__ att_s,
    const float* __restrict__ att_d, float* __restrict__ a1s,
    float* __restrict__ a1d, int N) {
  int wave = threadIdx.x >> 6, lane = threadIdx.x & 63;
  int n = blockIdx.x * 4 + wave;
  if (n >= N) return;
  uint2 u = *(const uint2*)(h1 + (size_t)n * 256 + lane * 4);
  float2 ab = __half22float2(*(const __half2*)&u.x);
  float2 cd = __half22float2(*(const __half2*)&u.y);
  float4 as = *(const float4*)(att_s + lane * 4);
  float4 ad = *(const float4*)(att_d + lane * 4);
  float vs = fmaf(ab.x, as.x, fmaf(ab.y, as.y, fmaf(cd.x, as.z, cd.y * as.w)));
  float vd = fmaf(ab.x, ad.x, fmaf(ab.y, ad.y, fmaf(cd.x, ad.z, cd.y * ad.w)));
#pragma unroll
  for (int off = 8; off > 0; off >>= 1) {
    vs += __shfl_down(vs, off, 16);
    vd += __shfl_down(vd, off, 16);
  }
  if ((lane & 15) == 0) {
    int head = lane >> 4;
    a1s[n * 4 + head] = vs;
    a1d[n * 4 + head] = vd;
  }
}

// ---------------- CSR build ----------------
__global__ void hist_deg(const int* __restrict__ dst, int* __restrict__ deg, int E, int ET) {
  int e = blockIdx.x * 256 + threadIdx.x;
  if (e >= ET) return;
  int d = (e < E) ? dst[e] : e - E;
  atomicAdd(deg + d, 1);
}

__global__ void scan_local(const int* __restrict__ deg, int* __restrict__ excl,
                           int* __restrict__ bsum, int N) {
  __shared__ int s[256];
  int i = blockIdx.x * 256 + threadIdx.x;
  int v = (i < N) ? deg[i] : 0;
  s[threadIdx.x] = v;
  __syncthreads();
  for (int off = 1; off < 256; off <<= 1) {
    int t = (threadIdx.x >= off) ? s[threadIdx.x - off] : 0;
    __syncthreads();
    s[threadIdx.x] += t;
    __syncthreads();
  }
  if (i < N) excl[i] = s[threadIdx.x] - v;
  if (threadIdx.x == 255) bsum[blockIdx.x] = s[255];
}

__global__ void scan_bsum(int* __restrict__ bsum, int nb) {
  __shared__ int s[256];
  int v = (threadIdx.x < nb) ? bsum[threadIdx.x] : 0;
  s[threadIdx.x] = v;
  __syncthreads();
  for (int off = 1; off < 256; off <<= 1) {
    int t = (threadIdx.x >= off) ? s[threadIdx.x - off] : 0;
    __syncthreads();
    s[threadIdx.x] += t;
    __syncthreads();
  }
  if (threadIdx.x < nb) bsum[threadIdx.x] = s[threadIdx.x] - v;  // exclusive
}

__global__ void scan_add(const int* __restrict__ excl, const int* __restrict__ bsum,
                         int* __restrict__ rowptr, int* __restrict__ cursor, int N, int ET) {
  int i = blockIdx.x * 256 + threadIdx.x;
  if (i < N) {
    int r = excl[i] + bsum[blockIdx.x];
    rowptr[i] = r;
    cursor[i] = r;
  }
  if (i == 0) rowptr[N] = ET;
}

__global__ void scatter_edges(const int* __restrict__ src, const int* __restrict__ dst,
                              int* __restrict__ cursor, int* __restrict__ elist, int E, int ET) {
  int e = blockIdx.x * 256 + threadIdx.x;
  if (e >= ET) return;
  int s, d;
  if (e < E) { s = src[e]; d = dst[e]; } else { s = d = e - E; }
  int pos = atomicAdd(cursor + d, 1);
  elist[pos] = s;
}

// ---------------- Kernel C: wave-per-node CSR aggregate, fused inline softmax +
// bias1 + ELU + GEMM2 (W2 in LDS) + layer-2 attention dots. 4 nodes/block. ----------
__global__ __launch_bounds__(256) void agg1_fused(
    const int* __restrict__ rowptr, const int* __restrict__ elist,
    const __half* __restrict__ h1, const float* __restrict__ a1s,
    const float* __restrict__ a1d, const float* __restrict__ b1,
    const float* __restrict__ W2, const float* __restrict__ as2,
    const float* __restrict__ ad2, float* __restrict__ h2,
    float* __restrict__ a2s, float* __restrict__ a2d, int N) {
  __shared__ float w2s[2560];
  const int t = threadIdx.x;
  for (int i = t; i < 2560; i += 256) w2s[i] = W2[i];
  __syncthreads();

  const int wave = t >> 6, lane = t & 63;
  const int n = blockIdx.x * 4 + wave;
  if (n >= N) return;
  const int row = rowptr[n];
  const int deg = rowptr[n + 1] - row;
  const int* el = elist + row;
  const int hidx = lane >> 4;            // head for channels lane*4..lane*4+3
  const float adh = a1d[n * 4 + hidx];   // uniform within 16-lane group

  float den = 0.f;
  float acc0 = 0.f, acc1 = 0.f, acc2 = 0.f, acc3 = 0.f;
  int j = 0;
  for (; j + 4 <= deg; j += 4) {
    int s0 = el[j], s1 = el[j + 1], s2 = el[j + 2], s3 = el[j + 3];
    float l0 = a1s[s0 * 4 + hidx] + adh;
    float l1 = a1s[s1 * 4 + hidx] + adh;
    float l2 = a1s[s2 * 4 + hidx] + adh;
    float l3 = a1s[s3 * 4 + hidx] + adh;
    uint2 u0 = *(const uint2*)(h1 + (size_t)s0 * 256 + lane * 4);
    uint2 u1 = *(const uint2*)(h1 + (size_t)s1 * 256 + lane * 4);
    uint2 u2 = *(const uint2*)(h1 + (size_t)s2 * 256 + lane * 4);
    uint2 u3 = *(const uint2*)(h1 + (size_t)s3 * 256 + lane * 4);
    l0 = l0 > 0.f ? l0 : NEG_SLOPE * l0;
    l1 = l1 > 0.f ? l1 : NEG_SLOPE * l1;
    l2 = l2 > 0.f ? l2 : NEG_SLOPE * l2;
    l3 = l3 > 0.f ? l3 : NEG_SLOPE * l3;
    float e0 = expf(l0), e1 = expf(l1), e2 = expf(l2), e3 = expf(l3);
    den += (e0 + e1) + (e2 + e3);
    {
      float2 a = __half22float2(*(const __half2*)&u0.x);
      float2 b = __half22float2(*(const __half2*)&u0.y);
      acc0 = fmaf(e0, a.x, acc0); acc1 = fmaf(e0, a.y, acc1);
      acc2 = fmaf(e0, b.x, acc2); acc3 = fmaf(e0, b.y, acc3);
    }
    {
      float2 a = __half22float2(*(const __half2*)&u1.x);
      float2 b = __half22float2(*(const __half2*)&u1.y);
      acc0 = fmaf(e1, a.x, acc0); acc1 = fmaf(e1, a.y, acc1);
      acc2 = fmaf(e1, b.x, acc2); acc3 = fmaf(e1, b.y, acc3);
    }
    {
      float2 a = __half22float2(*(const __half2*)&u2.x);
      float2 b = __half22float2(*(const __half2*)&u2.y);
      acc0 = fmaf(e2, a.x, acc0); acc1 = fmaf(e2, a.y, acc1);
      acc2 = fmaf(e2, b.x, acc2); acc3 = fmaf(e2, b.y, acc3);
    }
    {
      float2 a = __half22float2(*(const __half2*)&u3.x);
      float2 b = __half22float2(*(const __half2*)&u3.y);
      acc0 = fmaf(e3, a.x, acc0); acc1 = fmaf(e3, a.y, acc1);
      acc2 = fmaf(e3, b.x, acc2); acc3 = fmaf(e3, b.y, acc3);
    }
  }
  for (; j < deg; j++) {
    int s0 = el[j];
    float l0 = a1s[s0 * 4 + hidx] + adh;
    uint2 u0 = *(const uint2*)(h1 + (size_t)s0 * 256 + lane * 4);
    l0 = l0 > 0.f ? l0 : NEG_SLOPE * l0;
    float e0 = expf(l0);
    den += e0;
    float2 a = __half22float2(*(const __half2*)&u0.x);
    float2 b = __half22float2(*(const __half2*)&u0.y);
    acc0 = fmaf(e0, a.x, acc0); acc1 = fmaf(e0, a.y, acc1);
    acc2 = fmaf(e0, b.x, acc2); acc3 = fmaf(e0, b.y, acc3);
  }

  // epilogue: normalize + bias + ELU ; p[10] = sum_k c_k * W2[c_k][:] ; wave-reduce
  float inv = 1.0f / den;
  float4 bb = *(const float4*)(b1 + lane * 4);
  float c0 = fmaf(acc0, inv, bb.x);
  float c1 = fmaf(acc1, inv, bb.y);
  float c2 = fmaf(acc2, inv, bb.z);
  float c3 = fmaf(acc3, inv, bb.w);
  c0 = c0 > 0.f ? c0 : expm1f(c0);
  c1 = c1 > 0.f ? c1 : expm1f(c1);
  c2 = c2 > 0.f ? c2 : expm1f(c2);
  c3 = c3 > 0.f ? c3 : expm1f(c3);
  const float* w0 = w2s + (lane * 4 + 0) * 10;
  float p[10];
#pragma unroll
  for (int jj = 0; jj < 10; jj++)
    p[jj] = fmaf(c0, w0[jj], fmaf(c1, w0[10 + jj], fmaf(c2, w0[20 + jj], c3 * w0[30 + jj])));
#pragma unroll
  for (int jj = 0; jj < 10; jj++) {
#pragma unroll
    for (int off = 32; off > 0; off >>= 1) p[jj] += __shfl_down(p[jj], off, 64);
  }
  if (lane == 0) {
    float ds = 0.f, dd = 0.f;
#pragma unroll
    for (int jj = 0; jj < 10; jj++) {
      h2[(size_t)n * 16 + jj] = p[jj];
      ds = fmaf(p[jj], as2[jj], ds);
      dd = fmaf(p[jj], ad2[jj], dd);
    }
    a2s[n] = ds;
    a2d[n] = dd;
  }
}

// ---------------- Kernel F: wave-per-node layer-2 aggregate, inline softmax ----------
__global__ __launch_bounds__(256) void agg2_csr(
    const int* __restrict__ rowptr, const int* __restrict__ elist,
    const float* __restrict__ h2, const float* __restrict__ a2s,
    const float* __restrict__ a2d, const float* __restrict__ b2,
    float* __restrict__ out, int N) {
  int wave = threadIdx.x >> 6, lane = threadIdx.x & 63;
  int n = blockIdx.x * 4 + wave;
  if (n >= N) return;
  int row = rowptr[n];
  int deg = rowptr[n + 1] - row;
  const int* el = elist + row;
  float ad = a2d[n];
  int g = lane / 10;        // 0..5 active, lanes 60-63 idle
  int c = lane - g * 10;
  float den = 0.f, acc = 0.f;
  if (g < 6) {
    for (int j0 = 0; j0 < deg; j0 += 6) {
      int jj = j0 + g;
      if (jj < deg) {
        int s = el[jj];
        float l = a2s[s] + ad;
        l = l > 0.f ? l : NEG_SLOPE * l;
        float ev = expf(l);
        den += ev;
        acc = fmaf(ev, h2[(size_t)s * 16 + c], acc);
      }
    }
  }
  acc += __shfl_down(acc, 30, 64);
  den += __shfl_down(den, 30, 64);
  acc += __shfl_down(acc, 10, 64) + __shfl_down(acc, 20, 64);
  den += __shfl_down(den, 10, 64) + __shfl_down(den, 20, 64);
  if (lane < 10) out[(size_t)n * 10 + lane] = acc / den + b2[lane];
}

extern "C" void kernel_launch(void* const* d_in, const int* in_sizes, int n_in,
                              void* d_out, int out_size, void* d_ws, size_t ws_size,
                              hipStream_t stream) {
  const float* x = (const float*)d_in[0];
  const int* ei = (const int*)d_in[1];
  const float* W1 = (const float*)d_in[2];
  const float* as1 = (const float*)d_in[3];
  const float* ad1 = (const float*)d_in[4];
  const float* b1 = (const float*)d_in[5];
  const float* W2 = (const float*)d_in[6];
  const float* as2 = (const float*)d_in[7];
  const float* ad2 = (const float*)d_in[8];
  const float* b2 = (const float*)d_in[9];
  float* out = (float*)d_out;

  const int N = in_sizes[0] / 128;   // 50000
  const int E = in_sizes[1] / 2;     // 800000
  const int ET = E + N;
  const int* srcp = ei;
  const int* dstp = ei + E;

  char* ws = (char*)d_ws;
  size_t off = 0;
  auto alloc = [&](size_t nbytes) {
    char* p = ws + off;
    off += (nbytes + 255) & ~(size_t)255;
    return p;
  };
  __half* h1 = (__half*)alloc((size_t)N * 256 * 2);
  half8* Bpack = (half8*)alloc((size_t)4096 * 16);
  float* a1s = (float*)alloc((size_t)N * 4 * 4);
  float* a1d = (float*)alloc((size_t)N * 4 * 4);
  float* h2 = (float*)alloc((size_t)N * 16 * 4);
  float* a2sv = (float*)alloc((size_t)N * 4);
  float* a2dv = (float*)alloc((size_t)N * 4);
  int* deg = (int*)alloc((size_t)N * 4);
  int* excl = (int*)alloc((size_t)N * 4);
  int* bsum = (int*)alloc(256 * 4);
  int* rowptr = (int*)alloc((size_t)(N + 1) * 4);
  int* cursor = (int*)alloc((size_t)N * 4);
  int* elist = (int*)alloc((size_t)ET * 4);

  const int nb = (N + 255) / 256;

  hipMemsetAsync(deg, 0, (size_t)N * 4, stream);

  // CSR build
  hist_deg<<<(ET + 255) / 256, 256, 0, stream>>>(dstp, deg, E, ET);
  scan_local<<<nb, 256, 0, stream>>>(deg, excl, bsum, N);
  scan_bsum<<<1, 256, 0, stream>>>(bsum, nb);
  scan_add<<<nb, 256, 0, stream>>>(excl, bsum, rowptr, cursor, N, ET);
  scatter_edges<<<(ET + 255) / 256, 256, 0, stream>>>(srcp, dstp, cursor, elist, E, ET);

  // layer 1: MFMA GEMM + attention dots
  pack_W1<<<16, 256, 0, stream>>>(W1, Bpack);
  gemm1_mfma<<<(N / 16 + 3) / 4, 256, 0, stream>>>(x, Bpack, h1, N);
  att_dots<<<(N + 3) / 4, 256, 0, stream>>>(h1, as1, ad1, a1s, a1d, N);

  agg1_fused<<<(N + 3) / 4, 256, 0, stream>>>(rowptr, elist, h1, a1s, a1d, b1, W2,
                                              as2, ad2, h2, a2sv, a2dv, N);
  // layer 2
  agg2_csr<<<(N + 3) / 4, 256, 0, stream>>>(rowptr, elist, h2, a2sv, a2dv, b2, out, N);
}

// Round 6
// 308.271 us; speedup vs baseline: 5.0569x; 1.1175x over previous
//
#include <hip/hip_runtime.h>
#include <hip/hip_fp16.h>
#include <math.h>

#define NEG_SLOPE 0.2f
#define LOG2E 1.44269504088896f

#if __has_builtin(__builtin_amdgcn_exp2f)
#define EXP2(x) __builtin_amdgcn_exp2f(x)
#else
#define EXP2(x) exp2f(x)
#endif

typedef _Float16 half8 __attribute__((ext_vector_type(8)));
typedef float floatx4 __attribute__((ext_vector_type(4)));

// ---------------- pack W1 [128][256] fp32 -> f16 B-fragment order ----------------
__global__ __launch_bounds__(256) void pack_W1(const float* __restrict__ W1,
                                               half8* __restrict__ Bpack) {
  int tid = blockIdx.x * 256 + threadIdx.x;  // 4096 total
  int l = tid & 63;
  int ksnt = tid >> 6;
  int ks = ksnt & 3;
  int nt = ksnt >> 2;
  int col = nt * 16 + (l & 15);
  int krow = ks * 32 + (l >> 4) * 8;
  half8 v;
#pragma unroll
  for (int j = 0; j < 8; j++) v[j] = (_Float16)W1[(krow + j) * 256 + col];
  Bpack[tid] = v;
}

// ---------------- Kernel A: h1 = x @ W1 via MFMA, f16 out, fused att dots ----------
// wave per 16 nodes; 16 N-tiles x 4 K-steps of mfma_f32_16x16x32_f16.
// a1s/a1d written PRE-SCALED by log2e.
__global__ __launch_bounds__(256) void gemm1_mfma(
    const float* __restrict__ x, const half8* __restrict__ Bpack,
    const float* __restrict__ att_s, const float* __restrict__ att_d,
    __half* __restrict__ h1, float* __restrict__ a1s, float* __restrict__ a1d, int N) {
  const int wave = threadIdx.x >> 6, lane = threadIdx.x & 63;
  const int quad = lane >> 4, li = lane & 15;
  const int n0 = (blockIdx.x * 4 + wave) * 16;
  if (n0 >= N) return;
  floatx4 acc[16];
#pragma unroll
  for (int t = 0; t < 16; t++) acc[t] = (floatx4){0.f, 0.f, 0.f, 0.f};
  const float* xrow = x + (size_t)(n0 + li) * 128;
#pragma unroll
  for (int ks = 0; ks < 4; ks++) {
    float4 xa = *(const float4*)(xrow + ks * 32 + quad * 8);
    float4 xb = *(const float4*)(xrow + ks * 32 + quad * 8 + 4);
    half8 a;
    a[0] = (_Float16)xa.x; a[1] = (_Float16)xa.y;
    a[2] = (_Float16)xa.z; a[3] = (_Float16)xa.w;
    a[4] = (_Float16)xb.x; a[5] = (_Float16)xb.y;
    a[6] = (_Float16)xb.z; a[7] = (_Float16)xb.w;
#pragma unroll
    for (int nt = 0; nt < 16; nt++) {
      half8 b = Bpack[(nt * 4 + ks) * 64 + lane];
      acc[nt] = __builtin_amdgcn_mfma_f32_16x16x32_f16(a, b, acc[nt], 0, 0, 0);
    }
  }
  // store h1: C/D row(m)=quad*4+r, col(n)=nt*16+li
#pragma unroll
  for (int nt = 0; nt < 16; nt++) {
#pragma unroll
    for (int r = 0; r < 4; r++) {
      h1[(size_t)(n0 + quad * 4 + r) * 256 + nt * 16 + li] = __float2half(acc[nt][r]);
    }
  }
  // fused attention dots: channel ch = nt*16+li, head = nt>>2
  float as_f[16], ad_f[16];
#pragma unroll
  for (int nt = 0; nt < 16; nt++) {
    as_f[nt] = att_s[nt * 16 + li];
    ad_f[nt] = att_d[nt * 16 + li];
  }
#pragma unroll
  for (int r = 0; r < 4; r++) {
    int node = n0 + quad * 4 + r;
#pragma unroll
    for (int h = 0; h < 4; h++) {
      float vs = 0.f, vd = 0.f;
#pragma unroll
      for (int ntl = 0; ntl < 4; ntl++) {
        int nt = h * 4 + ntl;
        vs = fmaf(acc[nt][r], as_f[nt], vs);
        vd = fmaf(acc[nt][r], ad_f[nt], vd);
      }
#pragma unroll
      for (int off = 8; off > 0; off >>= 1) {
        vs += __shfl_down(vs, off, 16);
        vd += __shfl_down(vd, off, 16);
      }
      if (li == 0) {
        a1s[node * 4 + h] = vs * LOG2E;
        a1d[node * 4 + h] = vd * LOG2E;
      }
    }
  }
}

// ---------------- CSR build (self-loops placed analytically) ----------------
__global__ void hist_deg(const int* __restrict__ dst, int* __restrict__ deg, int E) {
  int e = blockIdx.x * 256 + threadIdx.x;
  if (e >= E) return;
  atomicAdd(deg + dst[e], 1);
}

__global__ void scan_local(const int* __restrict__ deg, int* __restrict__ excl,
                           int* __restrict__ bsum, int N) {
  __shared__ int s[256];
  int i = blockIdx.x * 256 + threadIdx.x;
  int v = (i < N) ? deg[i] + 1 : 0;  // +1 = self-loop
  s[threadIdx.x] = v;
  __syncthreads();
  for (int off = 1; off < 256; off <<= 1) {
    int t = (threadIdx.x >= off) ? s[threadIdx.x - off] : 0;
    __syncthreads();
    s[threadIdx.x] += t;
    __syncthreads();
  }
  if (i < N) excl[i] = s[threadIdx.x] - v;
  if (threadIdx.x == 255) bsum[blockIdx.x] = s[255];
}

__global__ void scan_bsum(int* __restrict__ bsum, int nb) {
  __shared__ int s[256];
  int v = (threadIdx.x < nb) ? bsum[threadIdx.x] : 0;
  s[threadIdx.x] = v;
  __syncthreads();
  for (int off = 1; off < 256; off <<= 1) {
    int t = (threadIdx.x >= off) ? s[threadIdx.x - off] : 0;
    __syncthreads();
    s[threadIdx.x] += t;
    __syncthreads();
  }
  if (threadIdx.x < nb) bsum[threadIdx.x] = s[threadIdx.x] - v;  // exclusive
}

__global__ void scan_add(const int* __restrict__ excl, const int* __restrict__ bsum,
                         int* __restrict__ rowptr, int* __restrict__ cursor,
                         int* __restrict__ elist, int N, int ET) {
  int i = blockIdx.x * 256 + threadIdx.x;
  if (i < N) {
    int r = excl[i] + bsum[blockIdx.x];
    rowptr[i] = r;
    elist[r] = i;        // self-loop edge placed first
    cursor[i] = r + 1;
  }
  if (i == 0) rowptr[N] = ET;
}

__global__ void scatter_edges(const int* __restrict__ src, const int* __restrict__ dst,
                              int* __restrict__ cursor, int* __restrict__ elist, int E) {
  int e = blockIdx.x * 256 + threadIdx.x;
  if (e >= E) return;
  int pos = atomicAdd(cursor + dst[e], 1);
  elist[pos] = src[e];
}

// ---------------- Kernel C: wave-per-node CSR aggregate, fast-exp inline softmax +
// bias1 + ELU + GEMM2 (W2 in LDS, stride 41) + layer-2 attention dots. -------------
__global__ __launch_bounds__(256) void agg1_fused(
    const int* __restrict__ rowptr, const int* __restrict__ elist,
    const __half* __restrict__ h1, const float* __restrict__ a1s,
    const float* __restrict__ a1d, const float* __restrict__ b1,
    const float* __restrict__ W2, const float* __restrict__ as2,
    const float* __restrict__ ad2, __half* __restrict__ h2,
    float* __restrict__ a2s, float* __restrict__ a2d, int N) {
  __shared__ float w2s[64 * 41];  // lane-stride 41: (lane*41)%32=(lane*9)%32, conflict-free
  const int t = threadIdx.x;
  for (int i = t; i < 2560; i += 256) {
    int ch = i / 10, jj = i - ch * 10;
    w2s[(ch >> 2) * 41 + (ch & 3) * 10 + jj] = W2[i];
  }
  __syncthreads();

  const int wave = t >> 6, lane = t & 63;
  const int n = blockIdx.x * 4 + wave;
  if (n >= N) return;
  const int row = rowptr[n];
  const int deg = rowptr[n + 1] - row;
  const int* el = elist + row;
  const int hidx = lane >> 4;
  const float adh = a1d[n * 4 + hidx];  // pre-scaled by log2e

  float den = 0.f;
  float acc0 = 0.f, acc1 = 0.f, acc2 = 0.f, acc3 = 0.f;
  int j = 0;
  for (; j + 4 <= deg; j += 4) {
    int s0 = el[j], s1 = el[j + 1], s2 = el[j + 2], s3 = el[j + 3];
    float l0 = a1s[s0 * 4 + hidx] + adh;
    float l1 = a1s[s1 * 4 + hidx] + adh;
    float l2 = a1s[s2 * 4 + hidx] + adh;
    float l3 = a1s[s3 * 4 + hidx] + adh;
    uint2 u0 = *(const uint2*)(h1 + (size_t)s0 * 256 + lane * 4);
    uint2 u1 = *(const uint2*)(h1 + (size_t)s1 * 256 + lane * 4);
    uint2 u2 = *(const uint2*)(h1 + (size_t)s2 * 256 + lane * 4);
    uint2 u3 = *(const uint2*)(h1 + (size_t)s3 * 256 + lane * 4);
    float e0 = EXP2(fmaxf(l0, NEG_SLOPE * l0));
    float e1 = EXP2(fmaxf(l1, NEG_SLOPE * l1));
    float e2 = EXP2(fmaxf(l2, NEG_SLOPE * l2));
    float e3 = EXP2(fmaxf(l3, NEG_SLOPE * l3));
    den += (e0 + e1) + (e2 + e3);
    {
      float2 a = __half22float2(*(const __half2*)&u0.x);
      float2 b = __half22float2(*(const __half2*)&u0.y);
      acc0 = fmaf(e0, a.x, acc0); acc1 = fmaf(e0, a.y, acc1);
      acc2 = fmaf(e0, b.x, acc2); acc3 = fmaf(e0, b.y, acc3);
    }
    {
      float2 a = __half22float2(*(const __half2*)&u1.x);
      float2 b = __half22float2(*(const __half2*)&u1.y);
      acc0 = fmaf(e1, a.x, acc0); acc1 = fmaf(e1, a.y, acc1);
      acc2 = fmaf(e1, b.x, acc2); acc3 = fmaf(e1, b.y, acc3);
    }
    {
      float2 a = __half22float2(*(const __half2*)&u2.x);
      float2 b = __half22float2(*(const __half2*)&u2.y);
      acc0 = fmaf(e2, a.x, acc0); acc1 = fmaf(e2, a.y, acc1);
      acc2 = fmaf(e2, b.x, acc2); acc3 = fmaf(e2, b.y, acc3);
    }
    {
      float2 a = __half22float2(*(const __half2*)&u3.x);
      float2 b = __half22float2(*(const __half2*)&u3.y);
      acc0 = fmaf(e3, a.x, acc0); acc1 = fmaf(e3, a.y, acc1);
      acc2 = fmaf(e3, b.x, acc2); acc3 = fmaf(e3, b.y, acc3);
    }
  }
  for (; j < deg; j++) {
    int s0 = el[j];
    float l0 = a1s[s0 * 4 + hidx] + adh;
    uint2 u0 = *(const uint2*)(h1 + (size_t)s0 * 256 + lane * 4);
    float e0 = EXP2(fmaxf(l0, NEG_SLOPE * l0));
    den += e0;
    float2 a = __half22float2(*(const __half2*)&u0.x);
    float2 b = __half22float2(*(const __half2*)&u0.y);
    acc0 = fmaf(e0, a.x, acc0); acc1 = fmaf(e0, a.y, acc1);
    acc2 = fmaf(e0, b.x, acc2); acc3 = fmaf(e0, b.y, acc3);
  }

  // epilogue: normalize + bias + ELU ; p[10] = sum_k c_k * W2[c_k][:] ; wave-reduce
  float inv = 1.0f / den;
  float4 bb = *(const float4*)(b1 + lane * 4);
  float c0 = fmaf(acc0, inv, bb.x);
  float c1 = fmaf(acc1, inv, bb.y);
  float c2 = fmaf(acc2, inv, bb.z);
  float c3 = fmaf(acc3, inv, bb.w);
  c0 = c0 > 0.f ? c0 : expm1f(c0);
  c1 = c1 > 0.f ? c1 : expm1f(c1);
  c2 = c2 > 0.f ? c2 : expm1f(c2);
  c3 = c3 > 0.f ? c3 : expm1f(c3);
  const float* w0 = w2s + lane * 41;
  float p[10];
#pragma unroll
  for (int jj = 0; jj < 10; jj++)
    p[jj] = fmaf(c0, w0[jj], fmaf(c1, w0[10 + jj], fmaf(c2, w0[20 + jj], c3 * w0[30 + jj])));
#pragma unroll
  for (int jj = 0; jj < 10; jj++) {
#pragma unroll
    for (int off = 32; off > 0; off >>= 1) p[jj] += __shfl_down(p[jj], off, 64);
  }
  if (lane == 0) {
    float ds = 0.f, dd = 0.f;
#pragma unroll
    for (int jj = 0; jj < 10; jj++) {
      h2[(size_t)n * 16 + jj] = __float2half(p[jj]);
      ds = fmaf(p[jj], as2[jj], ds);
      dd = fmaf(p[jj], ad2[jj], dd);
    }
    a2s[n] = ds * LOG2E;
    a2d[n] = dd * LOG2E;
  }
}

// ---------------- Kernel F: wave-per-node layer-2 aggregate, fast-exp softmax ------
__global__ __launch_bounds__(256) void agg2_csr(
    const int* __restrict__ rowptr, const int* __restrict__ elist,
    const __half* __restrict__ h2, const float* __restrict__ a2s,
    const float* __restrict__ a2d, const float* __restrict__ b2,
    float* __restrict__ out, int N) {
  int wave = threadIdx.x >> 6, lane = threadIdx.x & 63;
  int n = blockIdx.x * 4 + wave;
  if (n >= N) return;
  int row = rowptr[n];
  int deg = rowptr[n + 1] - row;
  const int* el = elist + row;
  float ad = a2d[n];  // pre-scaled
  int g = lane / 10;  // 0..5 active, lanes 60-63 idle
  int c = lane - g * 10;
  float den = 0.f, acc = 0.f;
  if (g < 6) {
    for (int jj = g; jj < deg; jj += 6) {
      int s = el[jj];
      float l = a2s[s] + ad;
      float ev = EXP2(fmaxf(l, NEG_SLOPE * l));
      den += ev;
      acc = fmaf(ev, __half2float(h2[(size_t)s * 16 + c]), acc);
    }
  }
  acc += __shfl_down(acc, 30, 64);
  den += __shfl_down(den, 30, 64);
  acc += __shfl_down(acc, 10, 64) + __shfl_down(acc, 20, 64);
  den += __shfl_down(den, 10, 64) + __shfl_down(den, 20, 64);
  if (lane < 10) out[(size_t)n * 10 + lane] = acc / den + b2[lane];
}

extern "C" void kernel_launch(void* const* d_in, const int* in_sizes, int n_in,
                              void* d_out, int out_size, void* d_ws, size_t ws_size,
                              hipStream_t stream) {
  const float* x = (const float*)d_in[0];
  const int* ei = (const int*)d_in[1];
  const float* W1 = (const float*)d_in[2];
  const float* as1 = (const float*)d_in[3];
  const float* ad1 = (const float*)d_in[4];
  const float* b1 = (const float*)d_in[5];
  const float* W2 = (const float*)d_in[6];
  const float* as2 = (const float*)d_in[7];
  const float* ad2 = (const float*)d_in[8];
  const float* b2 = (const float*)d_in[9];
  float* out = (float*)d_out;

  const int N = in_sizes[0] / 128;   // 50000
  const int E = in_sizes[1] / 2;     // 800000
  const int ET = E + N;
  const int* srcp = ei;
  const int* dstp = ei + E;

  char* ws = (char*)d_ws;
  size_t off = 0;
  auto alloc = [&](size_t nbytes) {
    char* p = ws + off;
    off += (nbytes + 255) & ~(size_t)255;
    return p;
  };
  __half* h1 = (__half*)alloc((size_t)N * 256 * 2);
  half8* Bpack = (half8*)alloc((size_t)4096 * 16);
  float* a1s = (float*)alloc((size_t)N * 4 * 4);
  float* a1d = (float*)alloc((size_t)N * 4 * 4);
  __half* h2 = (__half*)alloc((size_t)N * 16 * 2);
  float* a2sv = (float*)alloc((size_t)N * 4);
  float* a2dv = (float*)alloc((size_t)N * 4);
  int* deg = (int*)alloc((size_t)N * 4);
  int* excl = (int*)alloc((size_t)N * 4);
  int* bsum = (int*)alloc(256 * 4);
  int* rowptr = (int*)alloc((size_t)(N + 1) * 4);
  int* cursor = (int*)alloc((size_t)N * 4);
  int* elist = (int*)alloc((size_t)ET * 4);

  const int nb = (N + 255) / 256;

  hipMemsetAsync(deg, 0, (size_t)N * 4, stream);

  // CSR build (self-loops analytic)
  hist_deg<<<(E + 255) / 256, 256, 0, stream>>>(dstp, deg, E);
  scan_local<<<nb, 256, 0, stream>>>(deg, excl, bsum, N);
  scan_bsum<<<1, 256, 0, stream>>>(bsum, nb);
  scan_add<<<nb, 256, 0, stream>>>(excl, bsum, rowptr, cursor, elist, N, ET);
  scatter_edges<<<(E + 255) / 256, 256, 0, stream>>>(srcp, dstp, cursor, elist, E);

  // layer 1: MFMA GEMM with fused attention dots
  pack_W1<<<16, 256, 0, stream>>>(W1, Bpack);
  gemm1_mfma<<<(N / 16 + 3) / 4, 256, 0, stream>>>(x, Bpack, as1, ad1, h1, a1s, a1d, N);

  agg1_fused<<<(N + 3) / 4, 256, 0, stream>>>(rowptr, elist, h1, a1s, a1d, b1, W2,
                                              as2, ad2, h2, a2sv, a2dv, N);
  // layer 2
  agg2_csr<<<(N + 3) / 4, 256, 0, stream>>>(rowptr, elist, h2, a2sv, a2dv, b2, out, N);
}